// Round 6
// baseline (324.348 us; speedup 1.0000x reference)
//
#include <hip/hip_runtime.h>
#include <hip/hip_bf16.h>

// Problem constants
constexpr int CB = 2;     // batch
constexpr int CH = 128;   // H
constexpr int CW = 128;   // W
constexpr int CM = 8;     // heads

typedef __bf16 bf16x8 __attribute__((ext_vector_type(8)));
typedef float  f32x4  __attribute__((ext_vector_type(4)));
typedef unsigned short us8 __attribute__((ext_vector_type(8)));

__device__ __forceinline__ unsigned short f2bf(float f) {
  __hip_bfloat16 h = __float2bfloat16(f);
  return *reinterpret_cast<unsigned short*>(&h);
}
__device__ __forceinline__ float bf2f(unsigned short u) {
  union { unsigned int i; float f; } v;
  v.i = ((unsigned int)u) << 16;
  return v.f;
}

// ---------------------------------------------------------------------------
// Prep: (a) compose WC = Wq @ [Wd | Wa]  -> bf16-hi, transposed [j][k]
//       (b) transpose+round Wp, Wm       -> bf16-hi, [j][k]
//       (c) composed bias bda[j] = bq @ [Wd|Wa] + [bd|ba]   (fp32)
// All dot loops unrolled x8 to batch the dependent loads (latency fix).
// ---------------------------------------------------------------------------
__global__ __launch_bounds__(256) void prep_all_kernel(
    const float* __restrict__ Wq, const float* __restrict__ bq,
    const float* __restrict__ Wd, const float* __restrict__ bd,
    const float* __restrict__ Wa, const float* __restrict__ ba,
    const float* __restrict__ Wp, const float* __restrict__ Wm,
    unsigned short* __restrict__ WtDA, unsigned short* __restrict__ WtP,
    unsigned short* __restrict__ WtM, float* __restrict__ bda)
{
  const int blk = blockIdx.x, t = threadIdx.x;
  if (blk < 96) {                        // compose: 192*128 = 24576 elems
    const int idx = blk * 256 + t;
    const int j = idx >> 7, k = idx & 127;
    float s = 0.f;
    if (j < 128) {
#pragma unroll 8
      for (int i = 0; i < 128; ++i) s = fmaf(Wq[k * 128 + i], Wd[i * 128 + j], s);
    } else {
#pragma unroll 8
      for (int i = 0; i < 128; ++i) s = fmaf(Wq[k * 128 + i], Wa[i * 64 + (j - 128)], s);
    }
    WtDA[j * 128 + k] = f2bf(s);
  } else if (blk < 224) {                // transpose-round Wp, Wm
    const int idx = (blk - 96) * 256 + t;   // 0..32767
    if (idx < 16384) {
      const int k = idx >> 7, j = idx & 127;
      WtP[j * 128 + k] = f2bf(Wp[idx]);
    } else {
      const int i2 = idx - 16384;
      const int k = i2 >> 7, j = i2 & 127;
      WtM[j * 128 + k] = f2bf(Wm[i2]);
    }
  } else {                               // composed bias (192)
    if (t < 192) {
      const int j = t;
      float s = (j < 128) ? bd[j] : ba[j - 128];
      if (j < 128) {
#pragma unroll 8
        for (int i = 0; i < 128; ++i) s = fmaf(bq[i], Wd[i * 128 + j], s);
      } else {
#pragma unroll 8
        for (int i = 0; i < 128; ++i) s = fmaf(bq[i], Wa[i * 64 + (j - 128)], s);
      }
      bda[j] = s;
    }
  }
}

// ---------------------------------------------------------------------------
// Fused pre-sample GEMM, occupancy-oriented: 32-row blocks, 4 waves =
// 2 row-groups x 2 col-groups (each wave: 16 rows x half the columns).
//  blocks [0,1024):     z_q @ WtDA (J=192, bf16-hi A) -> dl2 (scrambled) + Alog
//  blocks [1024,+1280): {x0,x1} @ WtP (J=128, split hi+lo A) -> Wx (bf16)
// Fragment maps (m89-verified): A lane l -> row l&15, k (l>>4)*8+i;
// B lane l -> col l&15, k (l>>4)*8+i; D lane l -> col l&15, row (l>>4)*4+reg.
// dl2 layout: [row][kk][m][lp][2] (one contiguous slice per sample block).
// ---------------------------------------------------------------------------
__global__ __launch_bounds__(256) void pre_gemm_kernel(
    const float* __restrict__ z_q, const float* __restrict__ x0,
    const float* __restrict__ x1,
    const unsigned short* __restrict__ WtDA, const float* __restrict__ bda,
    const unsigned short* __restrict__ WtP,  const float* __restrict__ bp,
    float* __restrict__ dl2, float* __restrict__ Alog,
    unsigned short* __restrict__ Wx, int nZ)
{
  const int t   = threadIdx.x;
  const int wv  = t >> 6;
  const int l   = t & 63;
  const int lr  = l & 15;
  const int kg  = l >> 4;
  const int rgp = wv >> 1;     // row group 0/1
  const int cg  = wv & 1;      // col group 0/1
  const int blk = blockIdx.x;

  if (blk < nZ) {
    // ---------------- z-part: J=192, per-wave 6 jt ----------------
    const int r0 = blk * 32;
    const int arow = r0 + rgp * 16 + lr;
    const float* Ap = z_q + (size_t)arow * 128 + kg * 8;

    f32x4 acc[6];
#pragma unroll
    for (int jt = 0; jt < 6; ++jt) acc[jt] = (f32x4){0.f, 0.f, 0.f, 0.f};

#pragma unroll
    for (int k0 = 0; k0 < 128; k0 += 32) {
      const float4 f0 = *(const float4*)(Ap + k0);
      const float4 f1 = *(const float4*)(Ap + k0 + 4);
      const float ff[8] = {f0.x, f0.y, f0.z, f0.w, f1.x, f1.y, f1.z, f1.w};
      us8 uh;
#pragma unroll
      for (int i = 0; i < 8; ++i) uh[i] = f2bf(ff[i]);
      const bf16x8 ah = __builtin_bit_cast(bf16x8, uh);

#pragma unroll
      for (int jt = 0; jt < 6; ++jt) {
        const int col = (cg * 6 + jt) * 16 + lr;
        const bf16x8 bh = *(const bf16x8*)(WtDA + col * 128 + k0 + kg * 8);
        acc[jt] = __builtin_amdgcn_mfma_f32_16x16x32_bf16(ah, bh, acc[jt], 0, 0, 0);
      }
    }

    // scrambled column offset within dl2 row: [kk][m][lp][i]
    const int scol = ((lr >> 1) & 3) * 32 + ((lr >> 3) & 1) * 2 + (lr & 1);
#pragma unroll
    for (int jt = 0; jt < 6; ++jt) {
      const int jtg = cg * 6 + jt;
      if (jtg < 8) {
        const float bv = bda[jtg * 16 + lr];
#pragma unroll
        for (int ri = 0; ri < 4; ++ri) {
          const int row = r0 + rgp * 16 + kg * 4 + ri;
          dl2[(size_t)row * 128 + jtg * 4 + scol] = acc[jt][ri] + bv;
        }
      } else {
        const int col = (jtg - 8) * 16 + lr;
        const float bv = bda[128 + col];
#pragma unroll
        for (int ri = 0; ri < 4; ++ri) {
          const int row = r0 + rgp * 16 + kg * 4 + ri;
          Alog[(size_t)row * 64 + col] = acc[jt][ri] + bv;
        }
      }
    }
  } else {
    // ---------------- x-part: J=128, per-wave 4 jt, split hi+lo A ----------
    const int r0 = (blk - nZ) * 32;
    const float* A = (r0 < 8192) ? (x0 + (size_t)r0 * 128)
                                 : (x1 + (size_t)(r0 - 8192) * 128);
    const float* Ap = A + (size_t)(rgp * 16 + lr) * 128 + kg * 8;

    f32x4 acc[4];
#pragma unroll
    for (int jt = 0; jt < 4; ++jt) acc[jt] = (f32x4){0.f, 0.f, 0.f, 0.f};

#pragma unroll
    for (int k0 = 0; k0 < 128; k0 += 32) {
      const float4 f0 = *(const float4*)(Ap + k0);
      const float4 f1 = *(const float4*)(Ap + k0 + 4);
      const float ff[8] = {f0.x, f0.y, f0.z, f0.w, f1.x, f1.y, f1.z, f1.w};
      us8 uh, ul;
#pragma unroll
      for (int i = 0; i < 8; ++i) {
        const unsigned short hi = f2bf(ff[i]);
        uh[i] = hi;
        ul[i] = f2bf(ff[i] - bf2f(hi));
      }
      const bf16x8 ah = __builtin_bit_cast(bf16x8, uh);
      const bf16x8 al = __builtin_bit_cast(bf16x8, ul);

#pragma unroll
      for (int jt = 0; jt < 4; ++jt) {
        const int col = (cg * 4 + jt) * 16 + lr;
        const bf16x8 bh = *(const bf16x8*)(WtP + col * 128 + k0 + kg * 8);
        acc[jt] = __builtin_amdgcn_mfma_f32_16x16x32_bf16(ah, bh, acc[jt], 0, 0, 0);
        acc[jt] = __builtin_amdgcn_mfma_f32_16x16x32_bf16(al, bh, acc[jt], 0, 0, 0);
      }
    }

#pragma unroll
    for (int jt = 0; jt < 4; ++jt) {
      const int col = (cg * 4 + jt) * 16 + lr;
      const float bv = bp[col];
#pragma unroll
      for (int ri = 0; ri < 4; ++ri) {
        const int row = r0 + rgp * 16 + kg * 4 + ri;
        Wx[(size_t)row * 128 + col] = f2bf(acc[jt][ri] + bv);
      }
    }
  }
}

// ---------------------------------------------------------------------------
// Fused softmax + scrambled bilinear sampling + attention reduce + FINAL GEMM.
// One block per query q=(b,h,w), 128 threads: t = m*16 + c. The block computes
// the full P row (one value per thread), stages it in LDS, then computes
// out[q][t] = sum_k P[k]*Wm[k][t] + bm[t] (WtM columns are L1/L2-hot).
// Scramble: k' = h>>5 ; x' = (w>>5)+(h&31)*4 ; y' = (c>>2)+(w&31)*4
//           l' = (c>>1)&1 ; cv' = s + 8*(c&1) ; p_q batch = (b*M+m)%B
// ---------------------------------------------------------------------------
__global__ __launch_bounds__(128) void sample_attn_out_kernel(
    const float* __restrict__ Alog,          // [B*H*W, 64]
    const float* __restrict__ dl2,           // [B*H*W][kk][m][lp][2]
    const float* __restrict__ p_q,           // [B, H, W, 2]
    const unsigned short* __restrict__ Wx,   // rows 0..8191 = x0, 8192.. = x1
    const unsigned short* __restrict__ WtM,  // [128][128] bf16 (col-major W)
    const float* __restrict__ bm,
    float* __restrict__ out)                 // [B*H*W, 128]
{
  __shared__ float Psh[128];

  const int q = blockIdx.x;
  const int w = q & (CW - 1);
  const int h = (q >> 7) & (CH - 1);
  const int b = q >> 14;
  const int t = threadIdx.x;
  const int m = t >> 4;
  const int c = t & 15;

  const int kk   = h >> 5;
  const int xp   = (w >> 5) + ((h & 31) << 2);
  const int yp   = (c >> 2) + ((w & 31) << 2);
  const int lp   = (c >> 1) & 1;
  const int half = c & 1;

  // --- independent loads first: delta, ref point, logits ---
  const size_t qp = ((size_t)b * CH + yp) * CW + xp;
  const float2 dxy = *(const float2*)(dl2 + qp * 128 + kk * 32 + m * 4 + lp * 2);

  const int pb = (b * CM + m) % CB;  // faithful quirk
  const float2 pq2 = *(const float2*)(p_q + ((((size_t)pb * CH + yp) * CW + xp) * 2));

  const float* al = Alog + (size_t)q * 64 + m * 8;
  const float4 al0 = ((const float4*)al)[0];
  const float4 al1 = ((const float4*)al)[1];

  const int wl = lp ? 128 : 64;
  const int hl = wl;
  const int imgbase = lp ? (8192 + b * 16384) : (b * 4096);

  // grid_sample coords (align_corners=False, zeros padding), faithful math
  const float cx = pq2.x * (float)(wl - 1) + dxy.x;
  const float cy = pq2.y * (float)(hl - 1) + dxy.y;
  const float gx = 2.f * cx / (float)(wl - 1) - 1.f;
  const float gy = 2.f * cy / (float)(hl - 1) - 1.f;
  const float ix = ((gx + 1.f) * (float)wl - 1.f) * 0.5f;
  const float iy = ((gy + 1.f) * (float)hl - 1.f) * 0.5f;
  const float x0f = floorf(ix), y0f = floorf(iy);
  const float fx1 = ix - x0f, fy1 = iy - y0f;
  const float fx0 = 1.f - fx1, fy0 = 1.f - fy1;
  const int xi = (int)x0f, yi = (int)y0f;

  // clamped addresses + validity
  const float vx0 = ((unsigned)xi < (unsigned)wl) ? 1.f : 0.f;
  const float vx1 = ((unsigned)(xi + 1) < (unsigned)wl) ? 1.f : 0.f;
  const float vy0 = ((unsigned)yi < (unsigned)hl) ? 1.f : 0.f;
  const float vy1 = ((unsigned)(yi + 1) < (unsigned)hl) ? 1.f : 0.f;
  const int xc0 = min(max(xi, 0), wl - 1);
  const int xc1 = min(max(xi + 1, 0), wl - 1);
  const int yc0 = min(max(yi, 0), hl - 1);
  const int yc1 = min(max(yi + 1, 0), hl - 1);

  const unsigned short* base = Wx + (size_t)imgbase * 128 + (m * 16 + half * 8);
  const unsigned short* p00 = base + (size_t)(yc0 * wl + xc0) * 128;
  const unsigned short* p01 = base + (size_t)(yc0 * wl + xc1) * 128;
  const unsigned short* p10 = base + (size_t)(yc1 * wl + xc0) * 128;
  const unsigned short* p11 = base + (size_t)(yc1 * wl + xc1) * 128;

  // 4 independent 16B gathers, single clause
  const us8 g00 = *(const us8*)p00;
  const us8 g01 = *(const us8*)p01;
  const us8 g10 = *(const us8*)p10;
  const us8 g11 = *(const us8*)p11;

  // --- softmax (overlaps gather latency) ---
  float lg[8] = {al0.x, al0.y, al0.z, al0.w, al1.x, al1.y, al1.z, al1.w};
  float mx = -3.0e38f;
#pragma unroll
  for (int s = 0; s < 8; ++s) mx = fmaxf(mx, lg[s]);
  float se = 0.f;
#pragma unroll
  for (int s = 0; s < 8; ++s) { lg[s] = __expf(lg[s] - mx); se += lg[s]; }
  const float inv = 1.f / se;

  const float w00 = fy0 * fx0 * vy0 * vx0;
  const float w01 = fy0 * fx1 * vy0 * vx1;
  const float w10 = fy1 * fx0 * vy1 * vx0;
  const float w11 = fy1 * fx1 * vy1 * vx1;

  float o = 0.f;
#pragma unroll
  for (int s = 0; s < 8; ++s) {
    float v = w00 * bf2f(g00[s]);
    v = fmaf(w01, bf2f(g01[s]), v);
    v = fmaf(w10, bf2f(g10[s]), v);
    v = fmaf(w11, bf2f(g11[s]), v);
    o = fmaf(lg[s] * inv, v, o);
  }
  Psh[t] = o;
  __syncthreads();

  // --- final GEMM row: out[q][t] = bm[t] + sum_k Psh[k] * Wm[k][t] ---
  float acc = bm[t];
  const unsigned short* wc = WtM + t * 128;   // column t, k-contiguous
#pragma unroll
  for (int k0 = 0; k0 < 128; k0 += 8) {
    const us8 w8 = *(const us8*)(wc + k0);
    const float4 pA = *(const float4*)&Psh[k0];
    const float4 pB = *(const float4*)&Psh[k0 + 4];
    acc = fmaf(pA.x, bf2f(w8[0]), acc);
    acc = fmaf(pA.y, bf2f(w8[1]), acc);
    acc = fmaf(pA.z, bf2f(w8[2]), acc);
    acc = fmaf(pA.w, bf2f(w8[3]), acc);
    acc = fmaf(pB.x, bf2f(w8[4]), acc);
    acc = fmaf(pB.y, bf2f(w8[5]), acc);
    acc = fmaf(pB.z, bf2f(w8[6]), acc);
    acc = fmaf(pB.w, bf2f(w8[7]), acc);
  }
  out[(size_t)q * 128 + t] = acc;
}

// ---------------------------------------------------------------------------
extern "C" void kernel_launch(void* const* d_in, const int* in_sizes, int n_in,
                              void* d_out, int out_size, void* d_ws, size_t ws_size,
                              hipStream_t stream)
{
  const float* z_q = (const float*)d_in[0];
  const float* x0  = (const float*)d_in[1];
  const float* x1  = (const float*)d_in[2];
  const float* p_q = (const float*)d_in[3];
  const float* Wq  = (const float*)d_in[4];
  const float* bq  = (const float*)d_in[5];
  const float* Wd  = (const float*)d_in[6];
  const float* bd  = (const float*)d_in[7];
  const float* Wa  = (const float*)d_in[8];
  const float* ba  = (const float*)d_in[9];
  const float* Wp  = (const float*)d_in[10];
  const float* bp  = (const float*)d_in[11];
  const float* Wm  = (const float*)d_in[12];
  const float* bm  = (const float*)d_in[13];

  float* ws = (float*)d_ws;
  const int NQ = CB * CH * CW;   // 32768

  // bf16 weight area (ushorts): WtDA 24576 | WtP 16384 | WtM 16384
  unsigned short* Wts  = (unsigned short*)ws;
  unsigned short* WtDA = Wts;
  unsigned short* WtP  = Wts + 24576;
  unsigned short* WtM  = Wts + 40960;
  float* bda = ws + 28672;                        // 192 composed bias

  float* dl2  = ws + 28864;                       // [NQ,128] fp32 scrambled
  float* Alog = dl2 + 4194304;                    // [NQ,64] fp32
  unsigned short* Wx  = (unsigned short*)(Alog + 2097152);   // [40960,128] bf16

  prep_all_kernel<<<225, 256, 0, stream>>>(Wq, bq, Wd, bd, Wa, ba, Wp, Wm,
                                           WtDA, WtP, WtM, bda);

  const int nZ = NQ / 32;                         // 1024 z-part blocks
  pre_gemm_kernel<<<nZ + 1280, 256, 0, stream>>>(z_q, x0, x1, WtDA, bda,
                                                 WtP, bp, dl2, Alog, Wx, nZ);

  sample_attn_out_kernel<<<NQ, 128, 0, stream>>>(Alog, dl2, p_q, Wx,
                                                 WtM, bm, (float*)d_out);
}

// Round 7
// 182.835 us; speedup vs baseline: 1.7740x; 1.7740x over previous
//
#include <hip/hip_runtime.h>
#include <hip/hip_bf16.h>

// Problem constants
constexpr int CB = 2;     // batch
constexpr int CH = 128;   // H
constexpr int CW = 128;   // W
constexpr int CM = 8;     // heads

typedef __bf16 bf16x8 __attribute__((ext_vector_type(8)));
typedef float  f32x4  __attribute__((ext_vector_type(4)));
typedef unsigned short us8 __attribute__((ext_vector_type(8)));
typedef unsigned short us4 __attribute__((ext_vector_type(4)));

__device__ __forceinline__ unsigned short f2bf(float f) {
  __hip_bfloat16 h = __float2bfloat16(f);
  return *reinterpret_cast<unsigned short*>(&h);
}
__device__ __forceinline__ float bf2f(unsigned short u) {
  union { unsigned int i; float f; } v;
  v.i = ((unsigned int)u) << 16;
  return v.f;
}

// ---------------------------------------------------------------------------
// Prep (parallel): compose WC = Wq@[Wd|Wa] via split-k x4 + shfl reduce;
// transpose-round Wp,Wm; composed bias. 449 blocks.
// ---------------------------------------------------------------------------
__global__ __launch_bounds__(256) void prep_all_kernel(
    const float* __restrict__ Wq, const float* __restrict__ bq,
    const float* __restrict__ Wd, const float* __restrict__ bd,
    const float* __restrict__ Wa, const float* __restrict__ ba,
    const float* __restrict__ Wp, const float* __restrict__ Wm,
    unsigned short* __restrict__ WtDA, unsigned short* __restrict__ WtP,
    unsigned short* __restrict__ WtM, float* __restrict__ bda)
{
  const int blk = blockIdx.x, t = threadIdx.x;
  if (blk < 384) {                       // compose: 24576 outputs x 4 partials
    const int gtid = blk * 256 + t;
    const int idx = gtid >> 2;           // output index
    const int kc  = gtid & 3;            // k-chunk
    const int j = idx >> 7, k = idx & 127;
    const int i0 = kc * 32;
    float s = 0.f;
    if (j < 128) {
#pragma unroll
      for (int i = 0; i < 32; ++i)
        s = fmaf(Wq[k * 128 + i0 + i], Wd[(i0 + i) * 128 + j], s);
    } else {
#pragma unroll
      for (int i = 0; i < 32; ++i)
        s = fmaf(Wq[k * 128 + i0 + i], Wa[(i0 + i) * 64 + (j - 128)], s);
    }
    s += __shfl_xor(s, 1);
    s += __shfl_xor(s, 2);
    if (kc == 0) WtDA[j * 128 + k] = f2bf(s);
  } else if (blk < 448) {                // transpose-round Wp, Wm (2 each)
    int idx = (blk - 384) * 256 + t;     // 0..16383
    {
      const int k = idx >> 7, j = idx & 127;
      WtP[j * 128 + k] = f2bf(Wp[idx]);
    }
    {
      const int k = idx >> 7, j = idx & 127;
      WtM[j * 128 + k] = f2bf(Wm[idx]);
    }
  } else {                               // composed bias (192)
    if (t < 192) {
      const int j = t;
      float s = (j < 128) ? bd[j] : ba[j - 128];
      if (j < 128) {
#pragma unroll 8
        for (int i = 0; i < 128; ++i) s = fmaf(bq[i], Wd[i * 128 + j], s);
      } else {
#pragma unroll 8
        for (int i = 0; i < 128; ++i) s = fmaf(bq[i], Wa[i * 64 + (j - 128)], s);
      }
      bda[j] = s;
    }
  }
}

// ---------------------------------------------------------------------------
// LDS helpers: 16B-slot XOR swizzle (write and read sides identical).
// Layout: [row/col][128 ush] with slot16 ^= (row&7).
// ---------------------------------------------------------------------------
__device__ __forceinline__ void stage_B(const unsigned short* __restrict__ src,
                                        unsigned short* __restrict__ lds,
                                        int n_us8)  // cols*16
{
  for (int v = threadIdx.x; v < n_us8; v += 256) {
    const us8 d = *(const us8*)(src + v * 8);
    const int col = v >> 4;
    const int slot = (v & 15) ^ (col & 7);
    *(us8*)(lds + col * 128 + slot * 8) = d;
  }
}
__device__ __forceinline__ bf16x8 lds_frag(const unsigned short* __restrict__ lds,
                                           int rc, int ko)  // ko multiple of 8
{
  const int slot = (ko >> 3) ^ (rc & 7);
  return *(const bf16x8*)(lds + rc * 128 + slot * 8);
}

// ---------------------------------------------------------------------------
// Fused pre-sample GEMM, LDS-staged both operands, column-split blocks.
//  z-part (vb<1024): r0=(vb>>1)*64, cg=vb&1 -> cols [cg*96,+96) of [dl2|Alog]
//  x-part: r0=(i>>1)*64 over {x0,x1}, cg=i&1 -> cols [cg*64,+64) of Wx
// Fragment maps (m89-verified): A lane l -> row l&15, k (l>>4)*8+i;
// B lane l -> col l&15, k; D lane l -> col l&15, row (l>>4)*4+reg.
// dl2 layout: [row][kk][m][lp][2] (one contiguous slice per sample block).
// ---------------------------------------------------------------------------
__global__ __launch_bounds__(256) void pre_gemm_kernel(
    const float* __restrict__ z_q, const float* __restrict__ x0,
    const float* __restrict__ x1,
    const unsigned short* __restrict__ WtDA, const float* __restrict__ bda,
    const unsigned short* __restrict__ WtP,  const float* __restrict__ bp,
    float* __restrict__ dl2, float* __restrict__ Alog,
    unsigned short* __restrict__ Wx, int nZv)
{
  __shared__ __align__(16) unsigned short smem[24576];   // 48KB carved per part

  const int t  = threadIdx.x;
  const int w  = t >> 6;
  const int l  = t & 63;
  const int lr = l & 15;
  const int kg = l >> 4;
  const int blk = blockIdx.x;

  if (blk < nZv) {
    // ---------------- z-part ----------------
    unsigned short* Bsh = smem;            // 96 cols x 128 = 12288
    unsigned short* Ahi = smem + 12288;    // 64 rows x 128 = 8192
    const int r0 = (blk >> 1) * 64;
    const int cg = blk & 1;

    stage_B(WtDA + cg * 96 * 128, Bsh, 1536);
    {
      const float4* Ag = (const float4*)(z_q + (size_t)r0 * 128);
#pragma unroll
      for (int i = 0; i < 8; ++i) {
        const int v = t + i * 256;
        const float4 f = Ag[v];
        const int flat = v * 4;
        const int row = flat >> 7;
        const int ko  = flat & 127;
        us4 h;
        h[0] = f2bf(f.x); h[1] = f2bf(f.y); h[2] = f2bf(f.z); h[3] = f2bf(f.w);
        *(us4*)(Ahi + row * 128 + (((ko >> 3) ^ (row & 7)) << 3) + (ko & 7)) = h;
      }
    }
    __syncthreads();

    f32x4 acc[6];
#pragma unroll
    for (int jt = 0; jt < 6; ++jt) acc[jt] = (f32x4){0.f, 0.f, 0.f, 0.f};

    const int lrow = w * 16 + lr;
#pragma unroll
    for (int k0 = 0; k0 < 128; k0 += 32) {
      const int ko = k0 + kg * 8;
      const bf16x8 ah = lds_frag(Ahi, lrow, ko);
#pragma unroll
      for (int jt = 0; jt < 6; ++jt) {
        const bf16x8 bh = lds_frag(Bsh, jt * 16 + lr, ko);
        acc[jt] = __builtin_amdgcn_mfma_f32_16x16x32_bf16(ah, bh, acc[jt], 0, 0, 0);
      }
    }

    // scrambled column offset within dl2 row: [kk][m][lp][i]
    const int scol = ((lr >> 1) & 3) * 32 + ((lr >> 3) & 1) * 2 + (lr & 1);
#pragma unroll
    for (int jt = 0; jt < 6; ++jt) {
      const int jtg = cg * 6 + jt;
      if (jtg < 8) {
        const float bv = bda[jtg * 16 + lr];
#pragma unroll
        for (int ri = 0; ri < 4; ++ri) {
          const int row = r0 + w * 16 + kg * 4 + ri;
          dl2[(size_t)row * 128 + jtg * 4 + scol] = acc[jt][ri] + bv;
        }
      } else {
        const int col = (jtg - 8) * 16 + lr;
        const float bv = bda[128 + col];
#pragma unroll
        for (int ri = 0; ri < 4; ++ri) {
          const int row = r0 + w * 16 + kg * 4 + ri;
          Alog[(size_t)row * 64 + col] = acc[jt][ri] + bv;
        }
      }
    }
  } else {
    // ---------------- x-part: split hi+lo A ----------------
    unsigned short* Bsh = smem;            // 64 cols x 128 = 8192
    unsigned short* Ahi = smem + 8192;
    unsigned short* Alo = smem + 16384;
    const int i = blk - nZv;
    const int r0 = (i >> 1) * 64;
    const int cg = i & 1;
    const float* A = (r0 < 8192) ? (x0 + (size_t)r0 * 128)
                                 : (x1 + (size_t)(r0 - 8192) * 128);

    stage_B(WtP + cg * 64 * 128, Bsh, 1024);
    {
      const float4* Ag = (const float4*)A;
#pragma unroll
      for (int ii = 0; ii < 8; ++ii) {
        const int v = t + ii * 256;
        const float4 f = Ag[v];
        const int flat = v * 4;
        const int row = flat >> 7;
        const int ko  = flat & 127;
        const float ff[4] = {f.x, f.y, f.z, f.w};
        us4 h, lo;
#pragma unroll
        for (int u = 0; u < 4; ++u) {
          h[u]  = f2bf(ff[u]);
          lo[u] = f2bf(ff[u] - bf2f(h[u]));
        }
        const int off = row * 128 + (((ko >> 3) ^ (row & 7)) << 3) + (ko & 7);
        *(us4*)(Ahi + off) = h;
        *(us4*)(Alo + off) = lo;
      }
    }
    __syncthreads();

    f32x4 acc[4];
#pragma unroll
    for (int jt = 0; jt < 4; ++jt) acc[jt] = (f32x4){0.f, 0.f, 0.f, 0.f};

    const int lrow = w * 16 + lr;
#pragma unroll
    for (int k0 = 0; k0 < 128; k0 += 32) {
      const int ko = k0 + kg * 8;
      const bf16x8 ah = lds_frag(Ahi, lrow, ko);
      const bf16x8 al = lds_frag(Alo, lrow, ko);
#pragma unroll
      for (int jt = 0; jt < 4; ++jt) {
        const bf16x8 bh = lds_frag(Bsh, jt * 16 + lr, ko);
        acc[jt] = __builtin_amdgcn_mfma_f32_16x16x32_bf16(ah, bh, acc[jt], 0, 0, 0);
        acc[jt] = __builtin_amdgcn_mfma_f32_16x16x32_bf16(al, bh, acc[jt], 0, 0, 0);
      }
    }

#pragma unroll
    for (int jt = 0; jt < 4; ++jt) {
      const int col = cg * 64 + jt * 16 + lr;
      const float bv = bp[col];
#pragma unroll
      for (int ri = 0; ri < 4; ++ri) {
        const int row = r0 + w * 16 + kg * 4 + ri;
        Wx[(size_t)row * 128 + col] = f2bf(acc[jt][ri] + bv);
      }
    }
  }
}

// ---------------------------------------------------------------------------
// Final GEMM: out[NQ,128] = Pbf(bf16) @ WtM + bm. LDS-staged A and B,
// column-split blocks (1024 blocks, 64 rows x 64 cols each).
// ---------------------------------------------------------------------------
__global__ __launch_bounds__(256) void final_gemm_kernel(
    const unsigned short* __restrict__ Pbf,
    const unsigned short* __restrict__ WtM,
    const float* __restrict__ bm, float* __restrict__ out)
{
  __shared__ __align__(16) unsigned short smem[16384];   // 32KB
  unsigned short* Bsh = smem;          // 64 cols x 128
  unsigned short* Ash = smem + 8192;   // 64 rows x 128

  const int t  = threadIdx.x;
  const int w  = t >> 6;
  const int l  = t & 63;
  const int lr = l & 15;
  const int kg = l >> 4;
  const int r0 = (blockIdx.x >> 1) * 64;
  const int cg = blockIdx.x & 1;

  stage_B(WtM + cg * 64 * 128, Bsh, 1024);
  stage_B(Pbf + (size_t)r0 * 128, Ash, 1024);   // same swizzled copy (rows)
  __syncthreads();

  f32x4 acc[4];
#pragma unroll
  for (int jt = 0; jt < 4; ++jt) acc[jt] = (f32x4){0.f, 0.f, 0.f, 0.f};

  const int lrow = w * 16 + lr;
#pragma unroll
  for (int k0 = 0; k0 < 128; k0 += 32) {
    const int ko = k0 + kg * 8;
    const bf16x8 av = lds_frag(Ash, lrow, ko);
#pragma unroll
    for (int jt = 0; jt < 4; ++jt) {
      const bf16x8 bh = lds_frag(Bsh, jt * 16 + lr, ko);
      acc[jt] = __builtin_amdgcn_mfma_f32_16x16x32_bf16(av, bh, acc[jt], 0, 0, 0);
    }
  }

#pragma unroll
  for (int jt = 0; jt < 4; ++jt) {
    const int col = cg * 64 + jt * 16 + lr;
    const float bv = bm[col];
#pragma unroll
    for (int ri = 0; ri < 4; ++ri) {
      const int row = r0 + w * 16 + kg * 4 + ri;
      out[(size_t)row * 128 + col] = acc[jt][ri] + bv;
    }
  }
}

// ---------------------------------------------------------------------------
// Fused softmax + scrambled bilinear sampling + attention-weighted reduce.
// XCD-aware swizzle: logical q = (bid&7)*4096 + bid>>3 -> each XCD works a
// contiguous 4096-query chunk (gather footprint ~5MB ~ its private L2).
// One block per query q=(b,h,w), 128 threads: t = m*16 + c.
// Scramble: k' = h>>5 ; x' = (w>>5)+(h&31)*4 ; y' = (c>>2)+(w&31)*4
//           l' = (c>>1)&1 ; cv' = s + 8*(c&1) ; p_q batch = (b*M+m)%B
// ---------------------------------------------------------------------------
__global__ __launch_bounds__(128) void sample_attn_kernel(
    const float* __restrict__ Alog,          // [B*H*W, 64]
    const float* __restrict__ dl2,           // [B*H*W][kk][m][lp][2]
    const float* __restrict__ p_q,           // [B, H, W, 2]
    const unsigned short* __restrict__ Wx,   // rows 0..8191 = x0, 8192.. = x1
    unsigned short* __restrict__ Pbf)        // [B*H*W, 128] bf16
{
  const int bid = blockIdx.x;
  const int q = (bid & 7) * 4096 + (bid >> 3);   // bijective (32768 % 8 == 0)
  const int w = q & (CW - 1);
  const int h = (q >> 7) & (CH - 1);
  const int b = q >> 14;
  const int t = threadIdx.x;
  const int m = t >> 4;
  const int c = t & 15;

  const int kk   = h >> 5;
  const int xp   = (w >> 5) + ((h & 31) << 2);
  const int yp   = (c >> 2) + ((w & 31) << 2);
  const int lp   = (c >> 1) & 1;
  const int half = c & 1;

  // --- independent loads first: delta, ref point, logits ---
  const size_t qp = ((size_t)b * CH + yp) * CW + xp;
  const float2 dxy = *(const float2*)(dl2 + qp * 128 + kk * 32 + m * 4 + lp * 2);

  const int pb = (b * CM + m) % CB;  // faithful quirk
  const float2 pq2 = *(const float2*)(p_q + ((((size_t)pb * CH + yp) * CW + xp) * 2));

  const float* al = Alog + (size_t)q * 64 + m * 8;
  const float4 al0 = ((const float4*)al)[0];
  const float4 al1 = ((const float4*)al)[1];

  const int wl = lp ? 128 : 64;
  const int hl = wl;
  const int imgbase = lp ? (8192 + b * 16384) : (b * 4096);

  // grid_sample coords (align_corners=False, zeros padding), faithful math
  const float cx = pq2.x * (float)(wl - 1) + dxy.x;
  const float cy = pq2.y * (float)(hl - 1) + dxy.y;
  const float gx = 2.f * cx / (float)(wl - 1) - 1.f;
  const float gy = 2.f * cy / (float)(hl - 1) - 1.f;
  const float ix = ((gx + 1.f) * (float)wl - 1.f) * 0.5f;
  const float iy = ((gy + 1.f) * (float)hl - 1.f) * 0.5f;
  const float x0f = floorf(ix), y0f = floorf(iy);
  const float fx1 = ix - x0f, fy1 = iy - y0f;
  const float fx0 = 1.f - fx1, fy0 = 1.f - fy1;
  const int xi = (int)x0f, yi = (int)y0f;

  // clamped addresses + validity
  const float vx0 = ((unsigned)xi < (unsigned)wl) ? 1.f : 0.f;
  const float vx1 = ((unsigned)(xi + 1) < (unsigned)wl) ? 1.f : 0.f;
  const float vy0 = ((unsigned)yi < (unsigned)hl) ? 1.f : 0.f;
  const float vy1 = ((unsigned)(yi + 1) < (unsigned)hl) ? 1.f : 0.f;
  const int xc0 = min(max(xi, 0), wl - 1);
  const int xc1 = min(max(xi + 1, 0), wl - 1);
  const int yc0 = min(max(yi, 0), hl - 1);
  const int yc1 = min(max(yi + 1, 0), hl - 1);

  const unsigned short* base = Wx + (size_t)imgbase * 128 + (m * 16 + half * 8);
  const unsigned short* p00 = base + (size_t)(yc0 * wl + xc0) * 128;
  const unsigned short* p01 = base + (size_t)(yc0 * wl + xc1) * 128;
  const unsigned short* p10 = base + (size_t)(yc1 * wl + xc0) * 128;
  const unsigned short* p11 = base + (size_t)(yc1 * wl + xc1) * 128;

  // 4 independent 16B gathers, single clause
  const us8 g00 = *(const us8*)p00;
  const us8 g01 = *(const us8*)p01;
  const us8 g10 = *(const us8*)p10;
  const us8 g11 = *(const us8*)p11;

  // --- softmax (overlaps gather latency) ---
  float lg[8] = {al0.x, al0.y, al0.z, al0.w, al1.x, al1.y, al1.z, al1.w};
  float mx = -3.0e38f;
#pragma unroll
  for (int s = 0; s < 8; ++s) mx = fmaxf(mx, lg[s]);
  float se = 0.f;
#pragma unroll
  for (int s = 0; s < 8; ++s) { lg[s] = __expf(lg[s] - mx); se += lg[s]; }
  const float inv = 1.f / se;

  const float w00 = fy0 * fx0 * vy0 * vx0;
  const float w01 = fy0 * fx1 * vy0 * vx1;
  const float w10 = fy1 * fx0 * vy1 * vx0;
  const float w11 = fy1 * fx1 * vy1 * vx1;

  float o = 0.f;
#pragma unroll
  for (int s = 0; s < 8; ++s) {
    float v = w00 * bf2f(g00[s]);
    v = fmaf(w01, bf2f(g01[s]), v);
    v = fmaf(w10, bf2f(g10[s]), v);
    v = fmaf(w11, bf2f(g11[s]), v);
    o = fmaf(lg[s] * inv, v, o);
  }
  Pbf[(size_t)q * 128 + t] = f2bf(o);
}

// ---------------------------------------------------------------------------
extern "C" void kernel_launch(void* const* d_in, const int* in_sizes, int n_in,
                              void* d_out, int out_size, void* d_ws, size_t ws_size,
                              hipStream_t stream)
{
  const float* z_q = (const float*)d_in[0];
  const float* x0  = (const float*)d_in[1];
  const float* x1  = (const float*)d_in[2];
  const float* p_q = (const float*)d_in[3];
  const float* Wq  = (const float*)d_in[4];
  const float* bq  = (const float*)d_in[5];
  const float* Wd  = (const float*)d_in[6];
  const float* bd  = (const float*)d_in[7];
  const float* Wa  = (const float*)d_in[8];
  const float* ba  = (const float*)d_in[9];
  const float* Wp  = (const float*)d_in[10];
  const float* bp  = (const float*)d_in[11];
  const float* Wm  = (const float*)d_in[12];
  const float* bm  = (const float*)d_in[13];

  float* ws = (float*)d_ws;
  const int NQ = CB * CH * CW;   // 32768

  // bf16 weight area (ushorts): WtDA 24576 | WtP 16384 | WtM 16384
  unsigned short* Wts  = (unsigned short*)ws;
  unsigned short* WtDA = Wts;
  unsigned short* WtP  = Wts + 24576;
  unsigned short* WtM  = Wts + 40960;
  float* bda = ws + 28672;                        // 192 composed bias

  float* dl2  = ws + 28864;                       // [NQ,128] fp32 scrambled
  float* Alog = dl2 + 4194304;                    // [NQ,64] fp32
  unsigned short* Wx  = (unsigned short*)(Alog + 2097152);   // [40960,128] bf16
  unsigned short* Pbf = Wx + 5242880;             // [NQ,128] bf16

  prep_all_kernel<<<449, 256, 0, stream>>>(Wq, bq, Wd, bd, Wa, ba, Wp, Wm,
                                           WtDA, WtP, WtM, bda);

  const int nZv = 1024;                           // 512 row-tiles x 2 col-halves
  pre_gemm_kernel<<<nZv + 1280, 256, 0, stream>>>(z_q, x0, x1, WtDA, bda,
                                                  WtP, bp, dl2, Alog, Wx, nZv);

  sample_attn_kernel<<<NQ, 128, 0, stream>>>(Alog, dl2, p_q, Wx, Pbf);

  final_gemm_kernel<<<NQ / 32, 256, 0, stream>>>(Pbf, WtM, bm, (float*)d_out);
}